// Round 1
// baseline (223.460 us; speedup 1.0000x reference)
//
#include <hip/hip_runtime.h>
#include <math.h>

#define QPB 256   // queries per block == threads per block

// Fused 3-NN + interpolate.
// Each block owns QPB consecutive queries (all in one batch since nb % QPB == 0).
// Phase 1: stage the batch's mb known points into LDS as float4(px,py,pz,|p|^2).
// Phase 2: each thread brute-force scans all mb candidates, keeping top-3 via a
//          branchless sorted insert. d2 is computed with EXACTLY the reference's
//          rounding:  d2 = (qq - 2*dot) + pn, dot = ascending-k fma chain.
// Phase 3: stage idx/weights in LDS (reusing the points buffer), then interpolate
//          with lanes mapped to channels for fully coalesced gathers/stores.
extern "C" __global__ void __launch_bounds__(QPB)
knn3_interp_kernel(const float* __restrict__ xyz,
                   const float* __restrict__ new_xyz,
                   const float* __restrict__ feats,
                   float* __restrict__ out,
                   int mb, int nb, int C)
{
    extern __shared__ float4 s_pts[];      // mb float4 (also reused for idx/w staging)

    const int tid      = threadIdx.x;
    const int block_q0 = blockIdx.x * QPB;         // first global query of this block
    const int batch    = block_q0 / nb;
    const int known0   = batch * mb;               // first known-point row of this batch

    // ---- Phase 1: stage known points ----
    for (int p = tid; p < mb; p += QPB) {
        const float px = xyz[(size_t)(known0 + p) * 3 + 0];
        const float py = xyz[(size_t)(known0 + p) * 3 + 1];
        const float pz = xyz[(size_t)(known0 + p) * 3 + 2];
        float pn;
        {
#pragma clang fp contract(off)
            pn = (px * px + py * py) + pz * pz;    // matches np.sum(known*known,-1)
        }
        s_pts[p] = make_float4(px, py, pz, pn);
    }
    __syncthreads();

    // ---- Phase 2: brute-force top-3 scan ----
    const int gq = block_q0 + tid;
    const float qx = new_xyz[(size_t)gq * 3 + 0];
    const float qy = new_xyz[(size_t)gq * 3 + 1];
    const float qz = new_xyz[(size_t)gq * 3 + 2];
    float qq;
    {
#pragma clang fp contract(off)
        qq = (qx * qx + qy * qy) + qz * qz;        // matches np.sum(query*query,-1)
    }

    float b0 = INFINITY, b1 = INFINITY, b2 = INFINITY;
    int   i0 = 0, i1 = 0, i2 = 0;

#pragma unroll 8
    for (int p = 0; p < mb; ++p) {
        const float4 P = s_pts[p];                 // wave-broadcast LDS read
        // dot in ascending-k fma order (matches BLAS/XLA matmul)
        const float dot = fmaf(qz, P.z, fmaf(qy, P.y, qx * P.x));
        // 2*dot is exact, so fma(-2,dot,qq) == round(qq - 2*dot): same as reference
        const float d2  = fmaf(-2.0f, dot, qq) + P.w;

        const bool c0 = d2 < b0;
        const bool c1 = d2 < b1;
        const bool c2 = d2 < b2;
        b2 = c1 ? b1 : (c2 ? d2 : b2);
        i2 = c1 ? i1 : (c2 ? p  : i2);
        b1 = c0 ? b0 : (c1 ? d2 : b1);
        i1 = c0 ? i0 : (c1 ? p  : i1);
        b0 = c0 ? d2 : b0;
        i0 = c0 ? p  : i0;
    }

    // ---- weights (reference: sqrt(max(d2,0)), recip(+1e-8), normalize) ----
    const float da = sqrtf(fmaxf(b0, 0.0f));
    const float db = sqrtf(fmaxf(b1, 0.0f));
    const float dc = sqrtf(fmaxf(b2, 0.0f));
    const float ra = 1.0f / (da + 1e-8f);
    const float rb = 1.0f / (db + 1e-8f);
    const float rc = 1.0f / (dc + 1e-8f);
    float rs;
    {
#pragma clang fp contract(off)
        rs = (ra + rb) + rc;
    }
    const float wa = ra / rs, wb = rb / rs, wc = rc / rs;

    // ---- Phase 3: stage (idx, w) in LDS, then coalesced interpolation ----
    __syncthreads();                                // everyone done reading s_pts
    float* siw = (float*)s_pts;                     // QPB*3 floats
    int*   sii = (int*)(siw + QPB * 3);             // QPB*3 ints
    siw[tid]           = wa;
    siw[tid + QPB]     = wb;
    siw[tid + 2 * QPB] = wc;
    sii[tid]           = known0 + i0;
    sii[tid + QPB]     = known0 + i1;
    sii[tid + 2 * QPB] = known0 + i2;
    __syncthreads();

    const int wave = tid >> 6;
    const int lane = tid & 63;
    const int qpw  = QPB / 4;                       // queries per wave
    for (int j = 0; j < qpw; ++j) {
        const int qi = wave * qpw + j;
        const float wa_ = siw[qi];
        const float wb_ = siw[qi + QPB];
        const float wc_ = siw[qi + 2 * QPB];
        const int   ia  = sii[qi];
        const int   ib  = sii[qi + QPB];
        const int   ic  = sii[qi + 2 * QPB];
        const size_t ga = (size_t)ia * C;
        const size_t gb = (size_t)ib * C;
        const size_t gc = (size_t)ic * C;
        const size_t go = (size_t)(block_q0 + qi) * C;
        for (int c = lane; c < C; c += 64) {
            const float v = wa_ * feats[ga + c] + wb_ * feats[gb + c] + wc_ * feats[gc + c];
            out[go + c] = v;
        }
    }
}

extern "C" void kernel_launch(void* const* d_in, const int* in_sizes, int n_in,
                              void* d_out, int out_size, void* d_ws, size_t ws_size,
                              hipStream_t stream) {
    const float* xyz     = (const float*)d_in[0];
    const float* new_xyz = (const float*)d_in[2];
    const float* feats   = (const float*)d_in[4];
    float*       out     = (float*)d_out;

    const int n_known = in_sizes[0] / 3;
    const int B       = in_sizes[1];
    const int n_query = in_sizes[2] / 3;
    const int C       = in_sizes[4] / n_known;
    const int mb      = n_known / B;
    const int nb      = n_query / B;

    const int grid = n_query / QPB;
    size_t shmem = (size_t)mb * sizeof(float4);
    const size_t need_iw = (size_t)QPB * 6 * sizeof(float);
    if (shmem < need_iw) shmem = need_iw;

    knn3_interp_kernel<<<grid, QPB, shmem, stream>>>(xyz, new_xyz, feats, out, mb, nb, C);
}

// Round 2
// 140.664 us; speedup vs baseline: 1.5886x; 1.5886x over previous
//
#include <hip/hip_runtime.h>
#include <math.h>

#define THREADS 512   // 8 waves per block
#define WAVES   8     // candidate chunks (one per wave)
#define RQ      4     // queries per lane
#define QPB     256   // queries per block = 64 * RQ

// Fused 3-NN + interpolate, v2.
// Block = 512 threads (8 waves), owns QPB=256 consecutive queries.
// Phase 1: stage the batch's mb known points into LDS as float4(px,py,pz,|p|^2).
// Phase 2: wave w scans candidate chunk [w*mb/8, (w+1)*mb/8) for ALL 256 queries:
//          lane l holds queries {r*64+l, r=0..3} in registers (4 independent
//          chains -> ILP), LDS point read is wave-uniform broadcast amortized
//          over 4 pairs. Top-3 insert uses a min/med3 value network + cndmask
//          indices. d2 rounding is EXACTLY the reference's:
//          d2 = fma(-2, dot, qq) + pn, dot = ascending-k fma chain.
// Phase 3: merge the 8 per-chunk top-3s in LDS (chunk-ascending, strict '<'
//          => top_k lower-index tie-break preserved), compute weights.
// Phase 4: coalesced interpolation, lanes = channels.
extern "C" __global__ void __launch_bounds__(THREADS)
knn3_interp_kernel(const float* __restrict__ xyz,
                   const float* __restrict__ new_xyz,
                   const float* __restrict__ feats,
                   float* __restrict__ out,
                   int mb, int nb, int C)
{
    extern __shared__ float smem[];
    float4* s_pts = (float4*)smem;                 // mb float4

    const int tid = threadIdx.x;
    const int w   = tid >> 6;                      // wave id = chunk id
    const int l   = tid & 63;
    const int block_q0 = blockIdx.x * QPB;
    const int batch    = block_q0 / nb;
    const int known0   = batch * mb;

    // ---- Phase 1: stage known points ----
    for (int p = tid; p < mb; p += THREADS) {
        const float px = xyz[(size_t)(known0 + p) * 3 + 0];
        const float py = xyz[(size_t)(known0 + p) * 3 + 1];
        const float pz = xyz[(size_t)(known0 + p) * 3 + 2];
        float pn;
        {
#pragma clang fp contract(off)
            pn = (px * px + py * py) + pz * pz;    // matches np.sum(known*known,-1)
        }
        s_pts[p] = make_float4(px, py, pz, pn);
    }
    __syncthreads();

    // ---- Phase 2: chunked brute-force top-3 scan, 4 queries per lane ----
    float qx[RQ], qy[RQ], qz[RQ], qq[RQ];
#pragma unroll
    for (int r = 0; r < RQ; ++r) {
        const int gq = block_q0 + r * 64 + l;
        qx[r] = new_xyz[(size_t)gq * 3 + 0];
        qy[r] = new_xyz[(size_t)gq * 3 + 1];
        qz[r] = new_xyz[(size_t)gq * 3 + 2];
        {
#pragma clang fp contract(off)
            qq[r] = (qx[r] * qx[r] + qy[r] * qy[r]) + qz[r] * qz[r];
        }
    }

    float b0[RQ], b1[RQ], b2[RQ];
    int   i0[RQ], i1[RQ], i2[RQ];
#pragma unroll
    for (int r = 0; r < RQ; ++r) {
        b0[r] = INFINITY; b1[r] = INFINITY; b2[r] = INFINITY;
        i0[r] = 0; i1[r] = 0; i2[r] = 0;
    }

    const int clen  = mb / WAVES;
    const int p_beg = w * clen;
    const int p_end = p_beg + clen;

#pragma unroll 4
    for (int p = p_beg; p < p_end; ++p) {
        const float4 P = s_pts[p];                 // wave-uniform broadcast
#pragma unroll
        for (int r = 0; r < RQ; ++r) {
            const float dot = fmaf(qz[r], P.z, fmaf(qy[r], P.y, qx[r] * P.x));
            const float d2  = fmaf(-2.0f, dot, qq[r]) + P.w;

            const bool c0 = d2 < b0[r];
            const bool c1 = d2 < b1[r];
            const bool c2 = d2 < b2[r];
            const float n0 = fminf(d2, b0[r]);
            const float n1 = __builtin_amdgcn_fmed3f(d2, b0[r], b1[r]);
            const float n2 = __builtin_amdgcn_fmed3f(d2, b1[r], b2[r]);
            const int  j0 = c0 ? p : i0[r];
            const int  j1 = c0 ? i0[r] : (c1 ? p : i1[r]);
            const int  j2 = c1 ? i1[r] : (c2 ? p : i2[r]);
            b0[r] = n0; b1[r] = n1; b2[r] = n2;
            i0[r] = j0; i1[r] = j1; i2[r] = j2;
        }
    }

    // ---- Phase 3: merge 8 chunk-partials per query (in LDS, overlaying s_pts) ----
    __syncthreads();                               // everyone done reading s_pts
    float* sB  = smem;                             // [3][WAVES][QPB] floats
    int*   sI  = (int*)smem + 3 * WAVES * QPB;     // [3][WAVES][QPB] ints
    float* sFW = smem + 6 * WAVES * QPB;           // [3][QPB] final weights
    int*   sFI = (int*)sFW + 3 * QPB;              // [3][QPB] final indices

#pragma unroll
    for (int r = 0; r < RQ; ++r) {
        const int qb = r * 64 + l;
        sB[(0 * WAVES + w) * QPB + qb] = b0[r];
        sB[(1 * WAVES + w) * QPB + qb] = b1[r];
        sB[(2 * WAVES + w) * QPB + qb] = b2[r];
        sI[(0 * WAVES + w) * QPB + qb] = i0[r];
        sI[(1 * WAVES + w) * QPB + qb] = i1[r];
        sI[(2 * WAVES + w) * QPB + qb] = i2[r];
    }
    __syncthreads();

    if (tid < QPB) {
        float mv0 = sB[(0 * WAVES + 0) * QPB + tid];
        float mv1 = sB[(1 * WAVES + 0) * QPB + tid];
        float mv2 = sB[(2 * WAVES + 0) * QPB + tid];
        int   mi0 = sI[(0 * WAVES + 0) * QPB + tid];
        int   mi1 = sI[(1 * WAVES + 0) * QPB + tid];
        int   mi2 = sI[(2 * WAVES + 0) * QPB + tid];
        for (int c = 1; c < WAVES; ++c) {
#pragma unroll
            for (int k = 0; k < 3; ++k) {
                const float x  = sB[(k * WAVES + c) * QPB + tid];
                const int   xi = sI[(k * WAVES + c) * QPB + tid];
                const bool c0 = x < mv0;
                const bool c1 = x < mv1;
                const bool c2 = x < mv2;
                const float n0 = fminf(x, mv0);
                const float n1 = __builtin_amdgcn_fmed3f(x, mv0, mv1);
                const float n2 = __builtin_amdgcn_fmed3f(x, mv1, mv2);
                const int  j0 = c0 ? xi : mi0;
                const int  j1 = c0 ? mi0 : (c1 ? xi : mi1);
                const int  j2 = c1 ? mi1 : (c2 ? xi : mi2);
                mv0 = n0; mv1 = n1; mv2 = n2;
                mi0 = j0; mi1 = j1; mi2 = j2;
            }
        }

        // weights (reference: sqrt(max(d2,0)), recip(+1e-8), normalize)
        const float da = sqrtf(fmaxf(mv0, 0.0f));
        const float db = sqrtf(fmaxf(mv1, 0.0f));
        const float dc = sqrtf(fmaxf(mv2, 0.0f));
        const float ra = 1.0f / (da + 1e-8f);
        const float rb = 1.0f / (db + 1e-8f);
        const float rc = 1.0f / (dc + 1e-8f);
        float rs;
        {
#pragma clang fp contract(off)
            rs = (ra + rb) + rc;
        }
        sFW[0 * QPB + tid] = ra / rs;
        sFW[1 * QPB + tid] = rb / rs;
        sFW[2 * QPB + tid] = rc / rs;
        sFI[0 * QPB + tid] = known0 + mi0;
        sFI[1 * QPB + tid] = known0 + mi1;
        sFI[2 * QPB + tid] = known0 + mi2;
    }
    __syncthreads();

    // ---- Phase 4: coalesced interpolation, lanes = channels ----
    const int qpw = QPB / WAVES;                   // 32 queries per wave
    for (int j = 0; j < qpw; ++j) {
        const int qi = w * qpw + j;
        const float wa = sFW[0 * QPB + qi];
        const float wb = sFW[1 * QPB + qi];
        const float wc = sFW[2 * QPB + qi];
        const size_t ga = (size_t)sFI[0 * QPB + qi] * C;
        const size_t gb = (size_t)sFI[1 * QPB + qi] * C;
        const size_t gc = (size_t)sFI[2 * QPB + qi] * C;
        const size_t go = (size_t)(block_q0 + qi) * C;
        for (int c = l; c < C; c += 64) {
            out[go + c] = wa * feats[ga + c] + wb * feats[gb + c] + wc * feats[gc + c];
        }
    }
}

extern "C" void kernel_launch(void* const* d_in, const int* in_sizes, int n_in,
                              void* d_out, int out_size, void* d_ws, size_t ws_size,
                              hipStream_t stream) {
    const float* xyz     = (const float*)d_in[0];
    const float* new_xyz = (const float*)d_in[2];
    const float* feats   = (const float*)d_in[4];
    float*       out     = (float*)d_out;

    const int n_known = in_sizes[0] / 3;
    const int B       = in_sizes[1];
    const int n_query = in_sizes[2] / 3;
    const int C       = in_sizes[4] / n_known;
    const int mb      = n_known / B;
    const int nb      = n_query / B;

    const int grid = n_query / QPB;
    size_t shmem = (size_t)mb * sizeof(float4);
    const size_t need_merge = (size_t)(6 * WAVES * QPB + 6 * QPB) * sizeof(float);
    if (shmem < need_merge) shmem = need_merge;

    knn3_interp_kernel<<<grid, THREADS, shmem, stream>>>(xyz, new_xyz, feats, out, mb, nb, C);
}